// Round 1
// baseline (1373.479 us; speedup 1.0000x reference)
//
#include <hip/hip_runtime.h>
#include <hip/hip_bf16.h>
#include <stdint.h>

typedef _Float16 f16x8 __attribute__((ext_vector_type(8)));
typedef float f32x4 __attribute__((ext_vector_type(4)));

#define AS1 __attribute__((address_space(1)))
#define AS3 __attribute__((address_space(3)))

__device__ __forceinline__ void glds16(const void* g, void* l) {
  __builtin_amdgcn_global_load_lds((const AS1 unsigned int*)g,
                                   (AS3 unsigned int*)l, 16, 0, 0);
}

#define NEGV -1e9f

// ---------------- weight transpose: w[c][dout][din][k] f32 -> Wt[c*7+k][dout][din] f16
__global__ void k_wt(const float* __restrict__ w1, const float* __restrict__ w2,
                     _Float16* __restrict__ Wt) {
  int c = blockIdx.x >> 10;
  int dout = blockIdx.x & 1023;
  const float* w = (c == 0) ? w1 : w2;
  for (int t = 0; t < 4; ++t) {
    int din = threadIdx.x + t * 256;
    const float* s = w + ((size_t)dout * 1024 + din) * 7;
#pragma unroll
    for (int k = 0; k < 7; ++k)
      Wt[(((size_t)(c * 7 + k)) << 20) + (size_t)dout * 1024 + din] = (_Float16)s[k];
  }
}

// ---------------- zero halo rows of xT (rows 0..3 and 1028..1031 per b)
__global__ void k_zero_halo(_Float16* __restrict__ xT) {
  _Float16* p = xT + (size_t)blockIdx.x * (1032 * 1024);
  for (int i = threadIdx.x; i < 8192; i += 256) {
    int r = i >> 10;
    int cidx = i & 1023;
    int row = (r < 4) ? r : (1024 + r);
    p[(size_t)row * 1024 + cidx] = (_Float16)0.f;
  }
}

// ---------------- x[b][d][l] f32 -> xT[b][l+4][d] f16 (64x64 tiles)
__global__ void k_transpose(const float* __restrict__ x, _Float16* __restrict__ xT, int b0) {
  __shared__ float t[64][65];
  int bl = blockIdx.z;
  int l0 = blockIdx.x * 64, d0 = blockIdx.y * 64;
  const float* xb = x + (size_t)(b0 + bl) * 1024 * 1024;
  int c4 = (threadIdx.x & 15) * 4;
  int r0 = threadIdx.x >> 4;
#pragma unroll
  for (int s = 0; s < 4; ++s) {
    int row = r0 + s * 16;
    float4 v = *(const float4*)(xb + (size_t)(d0 + row) * 1024 + l0 + c4);
    t[row][c4 + 0] = v.x; t[row][c4 + 1] = v.y; t[row][c4 + 2] = v.z; t[row][c4 + 3] = v.w;
  }
  __syncthreads();
  _Float16* xo = xT + (size_t)bl * (1032 * 1024);
#pragma unroll
  for (int s = 0; s < 4; ++s) {
    int lrow = r0 + s * 16;
    union { ushort4 u; _Float16 h[4]; } pk;
    pk.h[0] = (_Float16)t[c4 + 0][lrow];
    pk.h[1] = (_Float16)t[c4 + 1][lrow];
    pk.h[2] = (_Float16)t[c4 + 2][lrow];
    pk.h[3] = (_Float16)t[c4 + 3][lrow];
    *(ushort4*)(xo + (size_t)(l0 + lrow + 4) * 1024 + d0 + c4) = pk.u;
  }
}

// ---------------- fused dual-conv GEMM: 128x128 tile, f16 MFMA
__launch_bounds__(256, 2)
__global__ void k_conv(const _Float16* __restrict__ xT, const _Float16* __restrict__ Wt,
                       float* __restrict__ obuf, float* __restrict__ abuf) {
  __shared__ _Float16 xs[2][136 * 64];
  __shared__ _Float16 wsm[2][128 * 64];
  int tid = threadIdx.x;
  int n0 = blockIdx.x * 128;
  int m0 = blockIdx.y * 128;
  int bz = blockIdx.z;
  int bl = bz >> 1, c = bz & 1;
  const _Float16* xb = xT + (size_t)bl * (1032 * 1024);
  const _Float16* wb = Wt + ((size_t)(c * 7) << 20);

  auto stageW = [&](int k, int cc, int buf) {
    const _Float16* src = wb + ((size_t)k << 20) + (size_t)m0 * 1024 + cc * 64;
    _Float16* dst = &wsm[buf][0];
#pragma unroll
    for (int ii = 0; ii < 4; ++ii) {
      int idx = ii * 256 + tid;
      int r = idx >> 3, cb = (idx & 7) << 3;
      glds16(src + (size_t)r * 1024 + (cb ^ ((r & 7) << 3)), dst + (size_t)idx * 8);
    }
  };
  auto stageX = [&](int cc, int buf) {
    const _Float16* src = xb + (size_t)n0 * 1024 + cc * 64;
    _Float16* dst = &xs[buf][0];
#pragma unroll
    for (int ii = 0; ii < 5; ++ii) {
      int idx = ii * 256 + tid;
      if (idx < 1088) {
        int r = idx >> 3, cb = (idx & 7) << 3;
        glds16(src + (size_t)r * 1024 + (cb ^ ((r & 7) << 3)), dst + (size_t)idx * 8);
      }
    }
  };

  f32x4 acc[4][4];
#pragma unroll
  for (int i = 0; i < 4; ++i)
#pragma unroll
    for (int j = 0; j < 4; ++j) acc[i][j] = (f32x4){0.f, 0.f, 0.f, 0.f};

  int lane = tid & 63, wid = tid >> 6;
  int wr = wid >> 1, wc = wid & 1;
  int col = lane & 15, kq = lane >> 4;
  int arow0 = wr * 64 + col;
  int swA = (col & 7) << 3;
  int brow0 = wc * 64 + col + 1;

  stageX(0, 0);
  stageW(0, 0, 0);
  __syncthreads();

  for (int it = 0; it < 112; ++it) {
    int cc = it / 7, k = it - cc * 7;
    if (it + 1 < 112) {
      int itn = it + 1;
      int ccn = itn / 7, kn = itn - ccn * 7;
      stageW(kn, ccn, itn & 1);
      if (ccn != cc) stageX(ccn, ccn & 1);
    }
    const _Float16* wp = &wsm[it & 1][0];
    const _Float16* xp = &xs[cc & 1][0];
    int brow = brow0 + k;
#pragma unroll
    for (int g = 0; g < 2; ++g) {
      int eo = g * 32 + kq * 8;
      f16x8 A[4], Bv[4];
#pragma unroll
      for (int i = 0; i < 4; ++i) {
        int r = arow0 + i * 16;
        A[i] = *(const f16x8*)(wp + (size_t)r * 64 + (eo ^ swA));
      }
#pragma unroll
      for (int j = 0; j < 4; ++j) {
        int r = brow + j * 16;
        Bv[j] = *(const f16x8*)(xp + (size_t)r * 64 + (eo ^ ((r & 7) << 3)));
      }
#pragma unroll
      for (int i = 0; i < 4; ++i)
#pragma unroll
        for (int j = 0; j < 4; ++j)
          acc[i][j] = __builtin_amdgcn_mfma_f32_16x16x32_f16(A[i], Bv[j], acc[i][j], 0, 0, 0);
    }
    __syncthreads();
  }

  float* ob = (c == 0 ? obuf : abuf) + (size_t)bl * 1024 * 1024;
  int dr0 = m0 + wr * 64 + kq * 4;
  int l0o = n0 + wc * 64 + col;
#pragma unroll
  for (int i = 0; i < 4; ++i)
#pragma unroll
    for (int j = 0; j < 4; ++j)
#pragma unroll
      for (int r = 0; r < 4; ++r)
        ob[(size_t)(dr0 + i * 16 + r) * 1024 + l0o + j * 16] = acc[i][j][r];
}

// ---------------- per-(b,d) row: sparsemax + weighted sum + max
__global__ void k_rows(const float* __restrict__ obuf, const float* __restrict__ abuf,
                       const void* __restrict__ maskp, const float* __restrict__ conv_b,
                       float* __restrict__ hbuf, int b0) {
  int wid = threadIdx.x >> 6, lane = threadIdx.x & 63;
  int row = blockIdx.x * 4 + wid;
  int bl = row >> 10, d = row & 1023;
  int bg = b0 + bl;

  // detect mask dtype: int32 0/1 values have zero bytes at offset%4 != 0
  unsigned wdet = ((const unsigned*)maskp)[lane];
  int isBool = __any((int)((wdet & 0xFFFFFF00u) != 0));

  const float* ar = abuf + (size_t)row * 1024;
  float z[16];
#pragma unroll
  for (int t = 0; t < 4; ++t) {
    float4 v = *(const float4*)(ar + t * 256 + lane * 4);
    z[t * 4 + 0] = v.x; z[t * 4 + 1] = v.y; z[t * 4 + 2] = v.z; z[t * 4 + 3] = v.w;
  }
  if (isBool) {
    const unsigned char* mb = (const unsigned char*)maskp + (size_t)bg * 1024;
#pragma unroll
    for (int t = 0; t < 4; ++t) {
      unsigned m4 = *(const unsigned*)(mb + t * 256 + lane * 4);
      if (!(m4 & 0x000000FFu)) z[t * 4 + 0] = NEGV;
      if (!(m4 & 0x0000FF00u)) z[t * 4 + 1] = NEGV;
      if (!(m4 & 0x00FF0000u)) z[t * 4 + 2] = NEGV;
      if (!(m4 & 0xFF000000u)) z[t * 4 + 3] = NEGV;
    }
  } else {
    const int* mi = (const int*)maskp + (size_t)bg * 1024;
#pragma unroll
    for (int t = 0; t < 4; ++t) {
      int4 m = *(const int4*)(mi + t * 256 + lane * 4);
      if (!m.x) z[t * 4 + 0] = NEGV;
      if (!m.y) z[t * 4 + 1] = NEGV;
      if (!m.z) z[t * 4 + 2] = NEGV;
      if (!m.w) z[t * 4 + 3] = NEGV;
    }
  }

  float zmax = z[0];
#pragma unroll
  for (int q = 1; q < 16; ++q) zmax = fmaxf(zmax, z[q]);
  for (int o = 32; o; o >>= 1) zmax = fmaxf(zmax, __shfl_xor(zmax, o));

  float lo = zmax - 1.0f, hi = zmax;
  for (int itn = 0; itn < 26; ++itn) {
    float mid = 0.5f * (lo + hi);
    float f = 0.f;
#pragma unroll
    for (int q = 0; q < 16; ++q) f += fmaxf(z[q] - mid, 0.f);
    for (int o = 32; o; o >>= 1) f += __shfl_xor(f, o);
    if (f >= 1.0f) lo = mid; else hi = mid;
  }
  float s = 0.f, kc = 0.f;
#pragma unroll
  for (int q = 0; q < 16; ++q)
    if (z[q] > lo) { s += z[q]; kc += 1.f; }
  for (int o = 32; o; o >>= 1) { s += __shfl_xor(s, o); kc += __shfl_xor(kc, o); }
  float tau = (s - 1.0f) / kc;

  const float* orow = obuf + (size_t)row * 1024;
  float o1 = 0.f, o2 = -1e30f;
#pragma unroll
  for (int t = 0; t < 4; ++t) {
    float4 v = *(const float4*)(orow + t * 256 + lane * 4);
    o1 += v.x * fmaxf(z[t * 4 + 0] - tau, 0.f); o2 = fmaxf(o2, v.x);
    o1 += v.y * fmaxf(z[t * 4 + 1] - tau, 0.f); o2 = fmaxf(o2, v.y);
    o1 += v.z * fmaxf(z[t * 4 + 2] - tau, 0.f); o2 = fmaxf(o2, v.z);
    o1 += v.w * fmaxf(z[t * 4 + 3] - tau, 0.f); o2 = fmaxf(o2, v.w);
  }
  for (int o = 32; o; o >>= 1) {
    o1 += __shfl_xor(o1, o);
    o2 = fmaxf(o2, __shfl_xor(o2, o));
  }
  if (lane == 0) {
    float bb = conv_b[d];
    hbuf[(size_t)bg * 2048 + d] = o1 + bb;
    hbuf[(size_t)bg * 2048 + 1024 + d] = o2 + bb;
  }
}

// ---------------- final MLP: lin -> relu -> bn -> out  (one wave per batch)
__global__ void k_final(const float* __restrict__ hbuf, const float* __restrict__ lw,
                        const float* __restrict__ lb, const float* __restrict__ bg,
                        const float* __restrict__ bb, const float* __restrict__ bm,
                        const float* __restrict__ bv, const float* __restrict__ ow,
                        const float* __restrict__ obv, float* __restrict__ out) {
  int b = blockIdx.x, lane = threadIdx.x;
  const float* hb = hbuf + (size_t)b * 2048;
  __shared__ float yy[32];
  for (int j = 0; j < 32; ++j) {
    float p = 0.f;
    for (int t = 0; t < 32; ++t) p += hb[t * 64 + lane] * lw[(size_t)j * 2048 + t * 64 + lane];
    for (int o = 32; o; o >>= 1) p += __shfl_xor(p, o);
    if (lane == 0) yy[j] = p + lb[j];
  }
  __syncthreads();
  float v = 0.f;
  if (lane < 32) {
    v = fmaxf(yy[lane], 0.f);
    v = (v - bm[lane]) * rsqrtf(bv[lane] + 1e-5f) * bg[lane] + bb[lane];
  }
  for (int o = 0; o < 11; ++o) {
    float t = (lane < 32) ? v * ow[o * 32 + lane] : 0.f;
    for (int off = 32; off; off >>= 1) t += __shfl_xor(t, off);
    if (lane == 0) out[b * 11 + o] = t + obv[o];
  }
}

static inline int imin(int a, int b) { return a < b ? a : b; }

extern "C" void kernel_launch(void* const* d_in, const int* in_sizes, int n_in,
                              void* d_out, int out_size, void* d_ws, size_t ws_size,
                              hipStream_t stream) {
  const float* x = (const float*)d_in[0];
  const void* mask = d_in[1];
  const float* w1 = (const float*)d_in[2];
  const float* b1 = (const float*)d_in[3];
  const float* w2 = (const float*)d_in[4];
  const float* lin_w = (const float*)d_in[6];
  const float* lin_b = (const float*)d_in[7];
  const float* bn_g = (const float*)d_in[8];
  const float* bn_b = (const float*)d_in[9];
  const float* bn_m = (const float*)d_in[10];
  const float* bn_v = (const float*)d_in[11];
  const float* out_w = (const float*)d_in[12];
  const float* out_b = (const float*)d_in[13];
  float* out = (float*)d_out;

  char* ws = (char*)d_ws;
  _Float16* Wt = (_Float16*)ws;
  size_t off = (size_t)2 * 7 * 1024 * 1024 * 2;   // 29,360,128
  float* hbuf = (float*)(ws + off);
  off += (size_t)32 * 2048 * 4;                   // + 262,144
  size_t fixed = off;
  size_t per_b = (size_t)1032 * 1024 * 2 + (size_t)2 * 1024 * 1024 * 4;

  long avail = (long)ws_size - (long)fixed;
  int bc = (avail > 0) ? (int)(avail / (long)per_b) : 1;
  if (bc < 1) bc = 1;
  if (bc > 32) bc = 32;

  _Float16* xT = (_Float16*)(ws + fixed);
  float* obuf = (float*)(ws + fixed + (size_t)bc * 1032 * 1024 * 2);
  float* abuf = obuf + (size_t)bc * 1024 * 1024;

  k_wt<<<2048, 256, 0, stream>>>(w1, w2, Wt);

  for (int b0 = 0; b0 < 32; b0 += bc) {
    int nb = imin(bc, 32 - b0);
    k_zero_halo<<<nb, 256, 0, stream>>>(xT);
    k_transpose<<<dim3(16, 16, nb), 256, 0, stream>>>(x, xT, b0);
    k_conv<<<dim3(8, 8, nb * 2), 256, 0, stream>>>(xT, Wt, obuf, abuf);
    k_rows<<<nb * 256, 256, 0, stream>>>(obuf, abuf, mask, b1, hbuf, b0);
  }
  k_final<<<32, 64, 0, stream>>>(hbuf, lin_w, lin_b, bn_g, bn_b, bn_m, bn_v, out_w, out_b, out);
}

// Round 6
// 1148.292 us; speedup vs baseline: 1.1961x; 1.1961x over previous
//
#include <hip/hip_runtime.h>
#include <hip/hip_bf16.h>
#include <stdint.h>

typedef _Float16 f16x8 __attribute__((ext_vector_type(8)));
typedef float f32x4 __attribute__((ext_vector_type(4)));

#define AS1 __attribute__((address_space(1)))
#define AS3 __attribute__((address_space(3)))

__device__ __forceinline__ void glds16(const void* g, void* l) {
  __builtin_amdgcn_global_load_lds((const AS1 unsigned int*)g,
                                   (AS3 unsigned int*)l, 16, 0, 0);
}

#define NEGV -1e9f

// ---------------- weight transpose: w[c][dout][din][k] f32 -> Wt[c*7+k][dout][din] f16
__global__ void k_wt(const float* __restrict__ w1, const float* __restrict__ w2,
                     _Float16* __restrict__ Wt) {
  int c = blockIdx.x >> 10;
  int dout = blockIdx.x & 1023;
  const float* w = (c == 0) ? w1 : w2;
  for (int t = 0; t < 4; ++t) {
    int din = threadIdx.x + t * 256;
    const float* s = w + ((size_t)dout * 1024 + din) * 7;
#pragma unroll
    for (int k = 0; k < 7; ++k)
      Wt[(((size_t)(c * 7 + k)) << 20) + (size_t)dout * 1024 + din] = (_Float16)s[k];
  }
}

// ---------------- zero halo rows of xT (rows 0..3 and 1028..1031 per b)
__global__ void k_zero_halo(_Float16* __restrict__ xT) {
  _Float16* p = xT + (size_t)blockIdx.x * (1032 * 1024);
  for (int i = threadIdx.x; i < 8192; i += 256) {
    int r = i >> 10;
    int cidx = i & 1023;
    int row = (r < 4) ? r : (1024 + r);
    p[(size_t)row * 1024 + cidx] = (_Float16)0.f;
  }
}

// ---------------- x[b][d][l] f32 -> xT[b][l+4][d] f16 (64x64 tiles)
__global__ void k_transpose(const float* __restrict__ x, _Float16* __restrict__ xT, int b0) {
  __shared__ float t[64][65];
  int bl = blockIdx.z;
  int l0 = blockIdx.x * 64, d0 = blockIdx.y * 64;
  const float* xb = x + (size_t)(b0 + bl) * 1024 * 1024;
  int c4 = (threadIdx.x & 15) * 4;
  int r0 = threadIdx.x >> 4;
#pragma unroll
  for (int s = 0; s < 4; ++s) {
    int row = r0 + s * 16;
    float4 v = *(const float4*)(xb + (size_t)(d0 + row) * 1024 + l0 + c4);
    t[row][c4 + 0] = v.x; t[row][c4 + 1] = v.y; t[row][c4 + 2] = v.z; t[row][c4 + 3] = v.w;
  }
  __syncthreads();
  _Float16* xo = xT + (size_t)bl * (1032 * 1024);
#pragma unroll
  for (int s = 0; s < 4; ++s) {
    int lrow = r0 + s * 16;
    union { ushort4 u; _Float16 h[4]; } pk;
    pk.h[0] = (_Float16)t[c4 + 0][lrow];
    pk.h[1] = (_Float16)t[c4 + 1][lrow];
    pk.h[2] = (_Float16)t[c4 + 2][lrow];
    pk.h[3] = (_Float16)t[c4 + 3][lrow];
    *(ushort4*)(xo + (size_t)(l0 + lrow + 4) * 1024 + d0 + c4) = pk.u;
  }
}

// ---------------- fused dual-conv GEMM: 256x256 tile, 8-phase schedule, f16 MFMA
// K-dim = 112 steps of 64 (16 din-chunks x 7 taps); tap shift folded into
// the per-step global base pointer of the X tile.
__launch_bounds__(512, 2)
__global__ void k_conv(const _Float16* __restrict__ xT, const _Float16* __restrict__ Wt,
                       float* __restrict__ obuf, float* __restrict__ abuf) {
  __shared__ _Float16 smem[2][2][16384];   // [buf][A=0/B=1][256*64] = 128 KiB
  int tid = threadIdx.x;
  int n0 = blockIdx.x * 256;
  int m0 = blockIdx.y * 256;
  int bz = blockIdx.z;
  int bl = bz >> 1, c = bz & 1;
  const _Float16* xb = xT + (size_t)bl * (1032 * 1024);
  const _Float16* wb = Wt + ((size_t)(c * 7) << 20);

  int lane = tid & 63, wid = tid >> 6;
  int wr = wid >> 2;            // 0..1  (M half: 128 rows)
  int wcol = wid & 3;           // 0..3  (N quarter: 64 cols)
  int col = lane & 15, kq = lane >> 4;
  int swA = (col & 7) << 3;     // f16-unit XOR swizzle (16B granules)

  // stage one 8KB chunk (64 rows x 64 f16): linear LDS dest, inverse-swizzled src
  auto stg = [&](const _Float16* src, _Float16* dst, int li) {
    int e = li * 512 + tid;
    int r = e >> 3, cb = (e & 7) << 3;
    glds16(src + (size_t)r * 1024 + (cb ^ ((r & 7) << 3)), dst + (size_t)e * 8);
  };

  f32x4 acc[8][4];
#pragma unroll
  for (int i = 0; i < 8; ++i)
#pragma unroll
    for (int j = 0; j < 4; ++j) acc[i][j] = (f32x4){0.f, 0.f, 0.f, 0.f};

  // prologue: stage tile 0 (cc=0, k=0), order B0..B3, A0,A2,A1,A3
  {
    const _Float16* pA = wb + (size_t)m0 * 1024;
    const _Float16* pB = xb + (size_t)(n0 + 1) * 1024;
    stg(pB, &smem[0][1][0], 0); stg(pB, &smem[0][1][0], 1);
    stg(pB, &smem[0][1][0], 2); stg(pB, &smem[0][1][0], 3);
    stg(pA, &smem[0][0][0], 0); stg(pA, &smem[0][0][0], 2);
    stg(pA, &smem[0][0][0], 1); stg(pA, &smem[0][0][0], 3);
  }
  asm volatile("s_waitcnt vmcnt(2)" ::: "memory");
  __builtin_amdgcn_s_barrier();

#define CPHASE(MB, S1, S2, TAIL)                                              \
  {                                                                           \
    f16x8 Af[2][2];                                                           \
    _Pragma("unroll") for (int i = 0; i < 2; ++i)                             \
    _Pragma("unroll") for (int g = 0; g < 2; ++g) {                           \
      int R = wr * 128 + (MB + i) * 16 + col;                                 \
      Af[i][g] = *(const f16x8*)(Ab + (size_t)R * 64 +                        \
                                 (((g << 5) + (kq << 3)) ^ swA));             \
    }                                                                         \
    S1; S2;                                                                   \
    __builtin_amdgcn_s_barrier();                                             \
    __builtin_amdgcn_s_setprio(1);                                            \
    _Pragma("unroll") for (int g = 0; g < 2; ++g)                             \
    _Pragma("unroll") for (int i = 0; i < 2; ++i)                             \
    _Pragma("unroll") for (int j = 0; j < 4; ++j)                             \
      acc[MB + i][j] = __builtin_amdgcn_mfma_f32_16x16x32_f16(                \
          Af[i][g], Bf[j][g], acc[MB + i][j], 0, 0, 0);                       \
    __builtin_amdgcn_s_setprio(0);                                            \
    TAIL;                                                                     \
    __builtin_amdgcn_s_barrier();                                             \
  }

  for (int t = 0; t < 112; ++t) {
    int cur = t & 1;
    const _Float16* Ab = &smem[cur][0][0];
    const _Float16* Bb = &smem[cur][1][0];
    _Float16* nAd = &smem[cur ^ 1][0][0];
    _Float16* nBd = &smem[cur ^ 1][1][0];
    const _Float16* nA = nullptr;
    const _Float16* nB = nullptr;
    bool hasNext = (t + 1 < 112);
    if (hasNext) {
      int s2 = t + 1, cc2 = s2 / 7, k2 = s2 - cc2 * 7;
      nA = wb + ((size_t)k2 << 20) + (size_t)m0 * 1024 + (size_t)cc2 * 64;
      nB = xb + (size_t)(n0 + k2 + 1) * 1024 + (size_t)cc2 * 64;
    }

    f16x8 Bf[4][2];
#pragma unroll
    for (int j = 0; j < 4; ++j)
#pragma unroll
      for (int g = 0; g < 2; ++g) {
        int R = wcol * 64 + j * 16 + col;
        Bf[j][g] = *(const f16x8*)(Bb + (size_t)R * 64 +
                                   (((g << 5) + (kq << 3)) ^ swA));
      }

    // phase 0: M-frags 0,1; stage next B0,B1
    CPHASE(0,
           if (hasNext) stg(nB, nBd, 0),
           if (hasNext) stg(nB, nBd, 1),
           );
    // phase 1: M-frags 2,3; stage next B2,B3; wait for current A1,A3
    CPHASE(2,
           if (hasNext) stg(nB, nBd, 2),
           if (hasNext) stg(nB, nBd, 3),
           if (hasNext) { asm volatile("s_waitcnt vmcnt(4)" ::: "memory"); }
           else        { asm volatile("s_waitcnt vmcnt(0)" ::: "memory"); });
    // phase 2: M-frags 4,5; stage next A0,A2
    CPHASE(4,
           if (hasNext) stg(nA, nAd, 0),
           if (hasNext) stg(nA, nAd, 2),
           );
    // phase 3: M-frags 6,7; stage next A1,A3; wait for next B*,A0,A2
    CPHASE(6,
           if (hasNext) stg(nA, nAd, 1),
           if (hasNext) stg(nA, nAd, 3),
           if (hasNext) { asm volatile("s_waitcnt vmcnt(2)" ::: "memory"); });
  }
#undef CPHASE

  float* ob = (c == 0 ? obuf : abuf) + (size_t)bl * 1024 * 1024;
  int r0 = m0 + wr * 128 + kq * 4;
  int c0 = n0 + wcol * 64 + col;
#pragma unroll
  for (int m = 0; m < 8; ++m)
#pragma unroll
    for (int j = 0; j < 4; ++j)
#pragma unroll
      for (int r = 0; r < 4; ++r)
        ob[(size_t)(r0 + m * 16 + r) * 1024 + c0 + j * 16] = acc[m][j][r];
}

// ---------------- per-(b,d) row: sparsemax + weighted sum + max
__global__ void k_rows(const float* __restrict__ obuf, const float* __restrict__ abuf,
                       const void* __restrict__ maskp, const float* __restrict__ conv_b,
                       float* __restrict__ hbuf, int b0) {
  int wid = threadIdx.x >> 6, lane = threadIdx.x & 63;
  int row = blockIdx.x * 4 + wid;
  int bl = row >> 10, d = row & 1023;
  int bg = b0 + bl;

  // detect mask dtype: int32 0/1 values have zero bytes at offset%4 != 0
  unsigned wdet = ((const unsigned*)maskp)[lane];
  int isBool = __any((int)((wdet & 0xFFFFFF00u) != 0));

  const float* ar = abuf + (size_t)row * 1024;
  float z[16];
#pragma unroll
  for (int t = 0; t < 4; ++t) {
    float4 v = *(const float4*)(ar + t * 256 + lane * 4);
    z[t * 4 + 0] = v.x; z[t * 4 + 1] = v.y; z[t * 4 + 2] = v.z; z[t * 4 + 3] = v.w;
  }
  if (isBool) {
    const unsigned char* mb = (const unsigned char*)maskp + (size_t)bg * 1024;
#pragma unroll
    for (int t = 0; t < 4; ++t) {
      unsigned m4 = *(const unsigned*)(mb + t * 256 + lane * 4);
      if (!(m4 & 0x000000FFu)) z[t * 4 + 0] = NEGV;
      if (!(m4 & 0x0000FF00u)) z[t * 4 + 1] = NEGV;
      if (!(m4 & 0x00FF0000u)) z[t * 4 + 2] = NEGV;
      if (!(m4 & 0xFF000000u)) z[t * 4 + 3] = NEGV;
    }
  } else {
    const int* mi = (const int*)maskp + (size_t)bg * 1024;
#pragma unroll
    for (int t = 0; t < 4; ++t) {
      int4 m = *(const int4*)(mi + t * 256 + lane * 4);
      if (!m.x) z[t * 4 + 0] = NEGV;
      if (!m.y) z[t * 4 + 1] = NEGV;
      if (!m.z) z[t * 4 + 2] = NEGV;
      if (!m.w) z[t * 4 + 3] = NEGV;
    }
  }

  float zmax = z[0];
#pragma unroll
  for (int q = 1; q < 16; ++q) zmax = fmaxf(zmax, z[q]);
  for (int o = 32; o; o >>= 1) zmax = fmaxf(zmax, __shfl_xor(zmax, o));

  float lo = zmax - 1.0f, hi = zmax;
  for (int itn = 0; itn < 26; ++itn) {
    float mid = 0.5f * (lo + hi);
    float f = 0.f;
#pragma unroll
    for (int q = 0; q < 16; ++q) f += fmaxf(z[q] - mid, 0.f);
    for (int o = 32; o; o >>= 1) f += __shfl_xor(f, o);
    if (f >= 1.0f) lo = mid; else hi = mid;
  }
  float s = 0.f, kc = 0.f;
#pragma unroll
  for (int q = 0; q < 16; ++q)
    if (z[q] > lo) { s += z[q]; kc += 1.f; }
  for (int o = 32; o; o >>= 1) { s += __shfl_xor(s, o); kc += __shfl_xor(kc, o); }
  float tau = (s - 1.0f) / kc;

  const float* orow = obuf + (size_t)row * 1024;
  float o1 = 0.f, o2 = -1e30f;
#pragma unroll
  for (int t = 0; t < 4; ++t) {
    float4 v = *(const float4*)(orow + t * 256 + lane * 4);
    o1 += v.x * fmaxf(z[t * 4 + 0] - tau, 0.f); o2 = fmaxf(o2, v.x);
    o1 += v.y * fmaxf(z[t * 4 + 1] - tau, 0.f); o2 = fmaxf(o2, v.y);
    o1 += v.z * fmaxf(z[t * 4 + 2] - tau, 0.f); o2 = fmaxf(o2, v.z);
    o1 += v.w * fmaxf(z[t * 4 + 3] - tau, 0.f); o2 = fmaxf(o2, v.w);
  }
  for (int o = 32; o; o >>= 1) {
    o1 += __shfl_xor(o1, o);
    o2 = fmaxf(o2, __shfl_xor(o2, o));
  }
  if (lane == 0) {
    float bb = conv_b[d];
    hbuf[(size_t)bg * 2048 + d] = o1 + bb;
    hbuf[(size_t)bg * 2048 + 1024 + d] = o2 + bb;
  }
}

// ---------------- final MLP: lin -> relu -> bn -> out  (one wave per batch)
__global__ void k_final(const float* __restrict__ hbuf, const float* __restrict__ lw,
                        const float* __restrict__ lb, const float* __restrict__ bg,
                        const float* __restrict__ bb, const float* __restrict__ bm,
                        const float* __restrict__ bv, const float* __restrict__ ow,
                        const float* __restrict__ obv, float* __restrict__ out) {
  int b = blockIdx.x, lane = threadIdx.x;
  const float* hb = hbuf + (size_t)b * 2048;
  __shared__ float yy[32];
  for (int j = 0; j < 32; ++j) {
    float p = 0.f;
    for (int t = 0; t < 32; ++t) p += hb[t * 64 + lane] * lw[(size_t)j * 2048 + t * 64 + lane];
    for (int o = 32; o; o >>= 1) p += __shfl_xor(p, o);
    if (lane == 0) yy[j] = p + lb[j];
  }
  __syncthreads();
  float v = 0.f;
  if (lane < 32) {
    v = fmaxf(yy[lane], 0.f);
    v = (v - bm[lane]) * rsqrtf(bv[lane] + 1e-5f) * bg[lane] + bb[lane];
  }
  for (int o = 0; o < 11; ++o) {
    float t = (lane < 32) ? v * ow[o * 32 + lane] : 0.f;
    for (int off = 32; off; off >>= 1) t += __shfl_xor(t, off);
    if (lane == 0) out[b * 11 + o] = t + obv[o];
  }
}

static inline int imin(int a, int b) { return a < b ? a : b; }

extern "C" void kernel_launch(void* const* d_in, const int* in_sizes, int n_in,
                              void* d_out, int out_size, void* d_ws, size_t ws_size,
                              hipStream_t stream) {
  const float* x = (const float*)d_in[0];
  const void* mask = d_in[1];
  const float* w1 = (const float*)d_in[2];
  const float* b1 = (const float*)d_in[3];
  const float* w2 = (const float*)d_in[4];
  const float* lin_w = (const float*)d_in[6];
  const float* lin_b = (const float*)d_in[7];
  const float* bn_g = (const float*)d_in[8];
  const float* bn_b = (const float*)d_in[9];
  const float* bn_m = (const float*)d_in[10];
  const float* bn_v = (const float*)d_in[11];
  const float* out_w = (const float*)d_in[12];
  const float* out_b = (const float*)d_in[13];
  float* out = (float*)d_out;

  char* ws = (char*)d_ws;
  _Float16* Wt = (_Float16*)ws;
  size_t off = (size_t)2 * 7 * 1024 * 1024 * 2;   // 29,360,128
  float* hbuf = (float*)(ws + off);
  off += (size_t)32 * 2048 * 4;                   // + 262,144
  size_t fixed = off;
  size_t per_b = (size_t)1032 * 1024 * 2 + (size_t)2 * 1024 * 1024 * 4;

  long avail = (long)ws_size - (long)fixed;
  int bc = (avail > 0) ? (int)(avail / (long)per_b) : 1;
  if (bc < 1) bc = 1;
  if (bc > 32) bc = 32;

  _Float16* xT = (_Float16*)(ws + fixed);
  float* obuf = (float*)(ws + fixed + (size_t)bc * 1032 * 1024 * 2);
  float* abuf = obuf + (size_t)bc * 1024 * 1024;

  k_wt<<<2048, 256, 0, stream>>>(w1, w2, Wt);

  for (int b0 = 0; b0 < 32; b0 += bc) {
    int nb = imin(bc, 32 - b0);
    k_zero_halo<<<nb, 256, 0, stream>>>(xT);
    k_transpose<<<dim3(16, 16, nb), 256, 0, stream>>>(x, xT, b0);
    k_conv<<<dim3(4, 4, nb * 2), 512, 0, stream>>>(xT, Wt, obuf, abuf);
    k_rows<<<nb * 256, 256, 0, stream>>>(obuf, abuf, mask, b1, hbuf, b0);
  }
  k_final<<<32, 64, 0, stream>>>(hbuf, lin_w, lin_b, bn_g, bn_b, bn_m, bn_v, out_w, out_b, out);
}